// Round 5
// baseline (254.397 us; speedup 1.0000x reference)
//
#include <hip/hip_runtime.h>
#include <hip/hip_bf16.h>

#define N 8192
#define IN_F 256
#define HEADS 4
#define HF 64
#define OUT_F 256

typedef __attribute__((ext_vector_type(8))) short short8;
typedef __attribute__((ext_vector_type(4))) float f32x4;

__device__ __forceinline__ float lrelu(float x) {
    return fmaxf(x, 0.0f) * 0.8f + x * 0.2f;
}
__device__ __forceinline__ short f2bf(float f) {
    union { __hip_bfloat16 h; short s; } u;
    u.h = __float2bfloat16(f);
    return u.s;
}
__device__ __forceinline__ float bf2f(unsigned short b) {
    union { unsigned u; float f; } v; v.u = ((unsigned)b) << 16;
    return v.f;
}
__device__ __forceinline__ unsigned pack_bf16(float p0, float p1) {
    union { __hip_bfloat162 b; unsigned u; } cv;
    cv.b = __float22bfloat162_rn(make_float2(p0, p1));
    return cv.u;
}

// K0: build BbT[c][k] bf16, c<256 -> W heads, c>=256 -> Wr
__global__ __launch_bounds__(256) void k_wcvt(
    const float* __restrict__ w, const float* __restrict__ wr,
    unsigned short* __restrict__ BbT)
{
    int c = blockIdx.x;
    int k = threadIdx.x;
    float v;
    if (c < 256) {
        int head = c >> 6, f = c & 63;
        v = w[((size_t)head * IN_F + k) * HF + f];
    } else {
        v = wr[(size_t)k * OUT_F + (c - 256)];
    }
    BbT[(size_t)c * IN_F + k] = (unsigned short)f2bf(v);
}

// K1: fused GEMM [8192x256]@[256x512] -> hT (cols<256, bf16, transposed) | out residual (cols>=256, f32)
__global__ __launch_bounds__(256) void k_gemm(
    const float* __restrict__ x, const unsigned short* __restrict__ BbT,
    const float* __restrict__ bias,
    unsigned short* __restrict__ hT, float* __restrict__ out)
{
    __shared__ unsigned short Asw[64 * 64];
    __shared__ unsigned short Bsw[128 * 64];
    int t = threadIdx.x;
    int m0 = blockIdx.x * 64;
    int bn = blockIdx.y;
    int w_ = t >> 6, l = t & 63;
    int wr_ = w_ >> 1, wc_ = w_ & 1;
    int ar = l & 15, g = l >> 4;

    f32x4 acc[2][4];
    #pragma unroll
    for (int m = 0; m < 2; ++m)
        #pragma unroll
        for (int n = 0; n < 4; ++n) acc[m][n] = (f32x4){0.f, 0.f, 0.f, 0.f};

    int srow = t >> 2, skq = (t & 3) * 16;
    int sc = t >> 1, sh = (t & 1) * 32;

    for (int kt = 0; kt < 4; ++kt) {
        const float* xs = x + (size_t)(m0 + srow) * IN_F + kt * 64 + skq;
        float4 xa = ((const float4*)xs)[0];
        float4 xb = ((const float4*)xs)[1];
        float4 xc = ((const float4*)xs)[2];
        float4 xd = ((const float4*)xs)[3];
        unsigned ae[8];
        ae[0] = pack_bf16(xa.x, xa.y); ae[1] = pack_bf16(xa.z, xa.w);
        ae[2] = pack_bf16(xb.x, xb.y); ae[3] = pack_bf16(xb.z, xb.w);
        ae[4] = pack_bf16(xc.x, xc.y); ae[5] = pack_bf16(xc.z, xc.w);
        ae[6] = pack_bf16(xd.x, xd.y); ae[7] = pack_bf16(xd.z, xd.w);
        int kb0 = (skq >> 3) ^ (srow & 7);
        int kb1 = ((skq >> 3) + 1) ^ (srow & 7);
        *(uint4*)&Asw[srow * 64 + kb0 * 8] = *(uint4*)&ae[0];
        *(uint4*)&Asw[srow * 64 + kb1 * 8] = *(uint4*)&ae[4];
        const unsigned short* bs = BbT + (size_t)(bn * 128 + sc) * IN_F + kt * 64 + sh;
        uint4 b0 = ((const uint4*)bs)[0];
        uint4 b1 = ((const uint4*)bs)[1];
        uint4 b2 = ((const uint4*)bs)[2];
        uint4 b3 = ((const uint4*)bs)[3];
        int hb = sh >> 3;
        *(uint4*)&Bsw[sc * 64 + ((hb + 0) ^ (sc & 7)) * 8] = b0;
        *(uint4*)&Bsw[sc * 64 + ((hb + 1) ^ (sc & 7)) * 8] = b1;
        *(uint4*)&Bsw[sc * 64 + ((hb + 2) ^ (sc & 7)) * 8] = b2;
        *(uint4*)&Bsw[sc * 64 + ((hb + 3) ^ (sc & 7)) * 8] = b3;
        __syncthreads();
        #pragma unroll
        for (int ks = 0; ks < 2; ++ks) {
            short8 af[2], bf[4];
            #pragma unroll
            for (int m = 0; m < 2; ++m) {
                int row = wr_ * 32 + m * 16 + ar;
                int kb = (ks * 4 + g) ^ (row & 7);
                af[m] = *(const short8*)&Asw[row * 64 + kb * 8];
            }
            #pragma unroll
            for (int n = 0; n < 4; ++n) {
                int c = wc_ * 64 + n * 16 + ar;
                int kb = (ks * 4 + g) ^ (c & 7);
                bf[n] = *(const short8*)&Bsw[c * 64 + kb * 8];
            }
            #pragma unroll
            for (int m = 0; m < 2; ++m)
                #pragma unroll
                for (int n = 0; n < 4; ++n)
                    acc[m][n] = __builtin_amdgcn_mfma_f32_16x16x32_bf16(af[m], bf[n], acc[m][n], 0, 0, 0);
        }
        __syncthreads();
    }
    #pragma unroll
    for (int m = 0; m < 2; ++m) {
        #pragma unroll
        for (int n = 0; n < 4; ++n) {
            int cg = bn * 128 + wc_ * 64 + n * 16 + ar;
            int mg0 = m0 + wr_ * 32 + m * 16 + g * 4;
            if (cg < 256) {
                int head = cg >> 6, f = cg & 63;
                unsigned pk[2];
                pk[0] = pack_bf16(acc[m][n][0], acc[m][n][1]);
                pk[1] = pack_bf16(acc[m][n][2], acc[m][n][3]);
                *(uint2*)(hT + (size_t)(head * HF + f) * N + mg0) = *(uint2*)pk;
            } else {
                float bb = bias[cg - 256];
                #pragma unroll
                for (int r = 0; r < 4; ++r)
                    out[(size_t)(mg0 + r) * OUT_F + (cg - 256)] = acc[m][n][r] + bb;
            }
        }
    }
}

// K2: coe_i/coe_j from hT (column-major dot, coalesced)
__global__ __launch_bounds__(256) void k_coe(
    const unsigned short* __restrict__ hT, const float* __restrict__ wi,
    const float* __restrict__ wj, float* __restrict__ coe_i, float* __restrict__ coe_j)
{
    int head = blockIdx.y;
    int n = blockIdx.x * 256 + threadIdx.x;
    const unsigned short* hp = hT + (size_t)head * HF * N + n;
    float si = 0.f, sj = 0.f;
    #pragma unroll 8
    for (int f = 0; f < HF; ++f) {
        float hv = bf2f(hp[(size_t)f * N]);
        si = fmaf(hv, wi[head * HF + f], si);
        sj = fmaf(hv, wj[head * HF + f], sj);
    }
    coe_i[head * N + n] = si;
    coe_j[head * N + n] = sj;
}

// K3: per head: maxB + column factor arrays F=exp(b), H=exp(0.2b)
__global__ __launch_bounds__(256) void k_cols(
    const float* __restrict__ coe_j, float* __restrict__ maxB,
    float* __restrict__ F, float* __restrict__ H)
{
    __shared__ float red[256];
    int head = blockIdx.x;
    int t = threadIdx.x;
    float m = -1e30f;
    for (int n = t; n < N; n += 256) {
        float b = coe_j[head * N + n];
        F[head * N + n] = __expf(b);
        H[head * N + n] = __expf(0.2f * b);
        m = fmaxf(m, b);
    }
    red[t] = m;
    __syncthreads();
    for (int s = 128; s > 0; s >>= 1) {
        if (t < s) red[t] = fmaxf(red[t], red[t + s]);
        __syncthreads();
    }
    if (t == 0) maxB[head] = red[0];
}

// K4: pack graph -> bits[jw][i]: bit k = graph[jw*32+k][i] > 0
__global__ __launch_bounds__(256) void k_pack(
    const int* __restrict__ graph, unsigned int* __restrict__ bits)
{
    int i = blockIdx.y * 256 + threadIdx.x;
    int jw = blockIdx.x;
    const int* gp = graph + (size_t)(jw * 32) * N + i;
    unsigned int word = 0;
    #pragma unroll
    for (int k = 0; k < 32; ++k)
        word |= (gp[(size_t)k * N] > 0 ? 1u : 0u) << k;
    bits[(size_t)jw * N + i] = word;
}

// P for 8 columns: p = max(Ei*F, Gi*H) (= exp(lrelu(a+b)-M)), mask by sign-shift, cvt_pk to bf16
__device__ __forceinline__ short8 makeP(
    const float4& fa, const float4& fb2, const float4& ha, const float4& hb2,
    unsigned int mk, float Ei, float Gi)
{
    float fv[8] = {fa.x, fa.y, fa.z, fa.w, fb2.x, fb2.y, fb2.z, fb2.w};
    float hv[8] = {ha.x, ha.y, ha.z, ha.w, hb2.x, hb2.y, hb2.z, hb2.w};
    union { short8 s8; unsigned u[4]; } A;
    #pragma unroll
    for (int jp = 0; jp < 4; ++jp) {
        float p0 = fmaxf(Ei * fv[2 * jp],     Gi * hv[2 * jp]);
        float p1 = fmaxf(Ei * fv[2 * jp + 1], Gi * hv[2 * jp + 1]);
        int s0 = ((int)(mk << (31 - 2 * jp))) >> 31;
        int s1 = ((int)(mk << (30 - 2 * jp))) >> 31;
        p0 = __int_as_float(__float_as_int(p0) & s0);
        p1 = __int_as_float(__float_as_int(p1) & s1);
        A.u[jp] = pack_bf16(p0, p1);
    }
    return A.s8;
}

// K5: flash aggregate. 512 thr = 8 waves; wave-pair (wrow, grp) splits even/odd 64-j tiles.
// 2-deep double buffer, ONE barrier per 128-j superstep; merge buffer aliases hbuf.
__global__ __launch_bounds__(512, 8) void k_att(
    const unsigned short* __restrict__ hT, const float* __restrict__ coe_i,
    const float* __restrict__ maxB, const float* __restrict__ F,
    const float* __restrict__ H, const unsigned int* __restrict__ bits,
    float* __restrict__ out)
{
    __shared__ char smem[32768];
    unsigned short* hb = (unsigned short*)smem;   // [buf:2][half:2][4096]
    float* mbuf = (float*)smem;                    // aliased merge buffer (used after final barrier)

    int t = threadIdx.x;
    int head = blockIdx.y;
    int i0 = blockIdx.x * 64;
    int w = t >> 6, l = t & 63;
    int wrow = w & 3, grp = w >> 2;
    int ar = l & 15, g = l >> 4, g8 = g * 8;

    int irow = i0 + wrow * 16 + ar;
    float a = coe_i[head * N + irow];
    float M = lrelu(a + maxB[head]);
    float Ei = __expf(a - M);
    float Gi = __expf(0.2f * a - M);

    f32x4 acc[4];
    #pragma unroll
    for (int fb = 0; fb < 4; ++fb) acc[fb] = (f32x4){0.f, 0.f, 0.f, 0.f};
    f32x4 accd = (f32x4){0.f, 0.f, 0.f, 0.f};

    short8 ones;
    #pragma unroll
    for (int k = 0; k < 8; ++k) ones[k] = (short)0x3F80;

    // staging role: thread stages 16 j of feature-row sf into half sbuf
    int sbuf = t >> 8;
    int u = t & 255;
    int sf = u >> 2, sj = (u & 3) * 16;
    const unsigned short* hrow = hT + ((size_t)(head * HF + sf) * N) + sj;
    int pg0 = ((sj >> 3) + 0) ^ (sf & 7);
    int pg1 = ((sj >> 3) + 1) ^ (sf & 7);
    int wo = sbuf * 4096 + sf * 64;

    const float* Fp = F + head * N + g8;
    const float* Hp = H + head * N + g8;
    const unsigned int* bp = bits + irow;

    // prolog: load superstep 0
    uint4 hv0 = *(const uint4*)(hrow + sbuf * 64);
    uint4 hv1 = *(const uint4*)(hrow + sbuf * 64 + 8);

    for (int s = 0; s < 64; ++s) {
        int jt = s * 128 + grp * 64;
        // compute-input loads for this step (independent of LDS)
        size_t jw = (size_t)(jt >> 5);
        unsigned int mk0 = bp[jw * N] >> g8;
        unsigned int mk1 = bp[(jw + 1) * N] >> g8;
        float4 f0 = *(const float4*)(Fp + jt);
        float4 f1 = *(const float4*)(Fp + jt + 4);
        float4 f2 = *(const float4*)(Fp + jt + 32);
        float4 f3 = *(const float4*)(Fp + jt + 36);
        float4 h0 = *(const float4*)(Hp + jt);
        float4 h1 = *(const float4*)(Hp + jt + 4);
        float4 h2 = *(const float4*)(Hp + jt + 32);
        float4 h3 = *(const float4*)(Hp + jt + 36);
        // write this superstep's staged tile (loaded last iteration)
        int bo = (s & 1) * 8192;
        *(uint4*)&hb[bo + wo + pg0 * 8] = hv0;
        *(uint4*)&hb[bo + wo + pg1 * 8] = hv1;
        // issue next superstep's stage loads (consumed next iteration)
        int sn = (s + 1 < 64) ? s + 1 : s;
        hv0 = *(const uint4*)(hrow + sn * 128 + sbuf * 64);
        hv1 = *(const uint4*)(hrow + sn * 128 + sbuf * 64 + 8);
        __syncthreads();   // single barrier: buf[s&1] visible; old reads of buf[(s+1)&1] done

        short8 af0 = makeP(f0, f1, h0, h1, mk0, Ei, Gi);
        short8 af1 = makeP(f2, f3, h2, h3, mk1, Ei, Gi);

        const unsigned short* rb = &hb[bo + grp * 4096];
        #pragma unroll
        for (int ss = 0; ss < 2; ++ss) {
            short8 af = ss ? af1 : af0;
            #pragma unroll
            for (int fb = 0; fb < 4; ++fb) {
                int row = fb * 16 + ar;
                int pg = (ss * 4 + g) ^ (ar & 7);
                short8 bfr = *(const short8*)&rb[row * 64 + pg * 8];
                acc[fb] = __builtin_amdgcn_mfma_f32_16x16x32_bf16(af, bfr, acc[fb], 0, 0, 0);
            }
            accd = __builtin_amdgcn_mfma_f32_16x16x32_bf16(af, ones, accd, 0, 0, 0);
        }
    }

    __syncthreads();               // all compute done before aliasing LDS as mbuf
    int mb = (wrow * 64 + l) * 21;
    if (grp == 1) {
        #pragma unroll
        for (int fb = 0; fb < 4; ++fb)
            #pragma unroll
            for (int r = 0; r < 4; ++r)
                mbuf[mb + fb * 4 + r] = acc[fb][r];
        #pragma unroll
        for (int r = 0; r < 4; ++r)
            mbuf[mb + 16 + r] = accd[r];
    }
    __syncthreads();
    if (grp == 0) {
        #pragma unroll
        for (int fb = 0; fb < 4; ++fb)
            #pragma unroll
            for (int r = 0; r < 4; ++r)
                acc[fb][r] += mbuf[mb + fb * 4 + r];
        #pragma unroll
        for (int r = 0; r < 4; ++r)
            accd[r] += mbuf[mb + 16 + r];
        #pragma unroll
        for (int r = 0; r < 4; ++r) {
            float inv = 1.0f / accd[r];
            int orow = i0 + wrow * 16 + g * 4 + r;
            float* op = out + (size_t)orow * OUT_F + head * HF + ar;
            #pragma unroll
            for (int fb = 0; fb < 4; ++fb)
                op[fb * 16] += acc[fb][r] * inv;
        }
    }
}

extern "C" void kernel_launch(void* const* d_in, const int* in_sizes, int n_in,
                              void* d_out, int out_size, void* d_ws, size_t ws_size,
                              hipStream_t stream) {
    const float* x     = (const float*)d_in[0];
    const int*   graph = (const int*)d_in[1];
    const float* w     = (const float*)d_in[2];
    const float* wi    = (const float*)d_in[3];
    const float* wj    = (const float*)d_in[4];
    const float* wr    = (const float*)d_in[5];
    const float* bias  = (const float*)d_in[6];
    float* out = (float*)d_out;

    char* ws = (char*)d_ws;
    unsigned short* hT  = (unsigned short*)(ws);                    // 4,194,304
    float* coe_i = (float*)(ws + 4194304);                          // 131072
    float* coe_j = (float*)(ws + 4325376);                          // 131072
    float* maxB  = (float*)(ws + 4456448);                          // 1024
    float* F     = (float*)(ws + 4457472);                          // 131072
    float* H     = (float*)(ws + 4588544);                          // 131072
    unsigned short* BbT = (unsigned short*)(ws + 4719616);          // 262144
    unsigned int* bits  = (unsigned int*)(ws + 4981760);            // 8,388,608

    k_wcvt<<<dim3(512), 256, 0, stream>>>(w, wr, BbT);
    k_gemm<<<dim3(128, 4), 256, 0, stream>>>(x, BbT, bias, hT, out);
    k_coe<<<dim3(32, 4), 256, 0, stream>>>(hT, wi, wj, coe_i, coe_j);
    k_cols<<<dim3(4), 256, 0, stream>>>(coe_j, maxB, F, H);
    k_pack<<<dim3(256, 32), 256, 0, stream>>>(graph, bits);
    k_att<<<dim3(N / 64, HEADS), 512, 0, stream>>>(hT, coe_i, maxB, F, H, bits, out);
}

// Round 6
// 178.425 us; speedup vs baseline: 1.4258x; 1.4258x over previous
//
#include <hip/hip_runtime.h>
#include <hip/hip_bf16.h>

#define N 8192
#define IN_F 256
#define HEADS 4
#define HF 64
#define OUT_F 256

typedef __attribute__((ext_vector_type(8))) short short8;
typedef __attribute__((ext_vector_type(4))) float f32x4;

__device__ __forceinline__ float lrelu(float x) {
    return fmaxf(x, 0.0f) * 0.8f + x * 0.2f;
}
__device__ __forceinline__ short f2bf(float f) {
    union { __hip_bfloat16 h; short s; } u;
    u.h = __float2bfloat16(f);
    return u.s;
}
__device__ __forceinline__ float bf2f(unsigned short b) {
    union { unsigned u; float f; } v; v.u = ((unsigned)b) << 16;
    return v.f;
}
__device__ __forceinline__ unsigned pack_bf16(float p0, float p1) {
    union { __hip_bfloat162 b; unsigned u; } cv;
    cv.b = __float22bfloat162_rn(make_float2(p0, p1));
    return cv.u;
}

// K0: build BbT[c][k] bf16, c<256 -> W heads, c>=256 -> Wr
__global__ __launch_bounds__(256) void k_wcvt(
    const float* __restrict__ w, const float* __restrict__ wr,
    unsigned short* __restrict__ BbT)
{
    int c = blockIdx.x;
    int k = threadIdx.x;
    float v;
    if (c < 256) {
        int head = c >> 6, f = c & 63;
        v = w[((size_t)head * IN_F + k) * HF + f];
    } else {
        v = wr[(size_t)k * OUT_F + (c - 256)];
    }
    BbT[(size_t)c * IN_F + k] = (unsigned short)f2bf(v);
}

// K1: fused GEMM [8192x256]@[256x512] -> hT (cols<256, bf16, transposed) | out residual (cols>=256, f32)
__global__ __launch_bounds__(256) void k_gemm(
    const float* __restrict__ x, const unsigned short* __restrict__ BbT,
    const float* __restrict__ bias,
    unsigned short* __restrict__ hT, float* __restrict__ out)
{
    __shared__ unsigned short Asw[64 * 64];
    __shared__ unsigned short Bsw[128 * 64];
    int t = threadIdx.x;
    int m0 = blockIdx.x * 64;
    int bn = blockIdx.y;
    int w_ = t >> 6, l = t & 63;
    int wr_ = w_ >> 1, wc_ = w_ & 1;
    int ar = l & 15, g = l >> 4;

    f32x4 acc[2][4];
    #pragma unroll
    for (int m = 0; m < 2; ++m)
        #pragma unroll
        for (int n = 0; n < 4; ++n) acc[m][n] = (f32x4){0.f, 0.f, 0.f, 0.f};

    int srow = t >> 2, skq = (t & 3) * 16;
    int sc = t >> 1, sh = (t & 1) * 32;

    for (int kt = 0; kt < 4; ++kt) {
        const float* xs = x + (size_t)(m0 + srow) * IN_F + kt * 64 + skq;
        float4 xa = ((const float4*)xs)[0];
        float4 xb = ((const float4*)xs)[1];
        float4 xc = ((const float4*)xs)[2];
        float4 xd = ((const float4*)xs)[3];
        unsigned ae[8];
        ae[0] = pack_bf16(xa.x, xa.y); ae[1] = pack_bf16(xa.z, xa.w);
        ae[2] = pack_bf16(xb.x, xb.y); ae[3] = pack_bf16(xb.z, xb.w);
        ae[4] = pack_bf16(xc.x, xc.y); ae[5] = pack_bf16(xc.z, xc.w);
        ae[6] = pack_bf16(xd.x, xd.y); ae[7] = pack_bf16(xd.z, xd.w);
        int kb0 = (skq >> 3) ^ (srow & 7);
        int kb1 = ((skq >> 3) + 1) ^ (srow & 7);
        *(uint4*)&Asw[srow * 64 + kb0 * 8] = *(uint4*)&ae[0];
        *(uint4*)&Asw[srow * 64 + kb1 * 8] = *(uint4*)&ae[4];
        const unsigned short* bs = BbT + (size_t)(bn * 128 + sc) * IN_F + kt * 64 + sh;
        uint4 b0 = ((const uint4*)bs)[0];
        uint4 b1 = ((const uint4*)bs)[1];
        uint4 b2 = ((const uint4*)bs)[2];
        uint4 b3 = ((const uint4*)bs)[3];
        int hb = sh >> 3;
        *(uint4*)&Bsw[sc * 64 + ((hb + 0) ^ (sc & 7)) * 8] = b0;
        *(uint4*)&Bsw[sc * 64 + ((hb + 1) ^ (sc & 7)) * 8] = b1;
        *(uint4*)&Bsw[sc * 64 + ((hb + 2) ^ (sc & 7)) * 8] = b2;
        *(uint4*)&Bsw[sc * 64 + ((hb + 3) ^ (sc & 7)) * 8] = b3;
        __syncthreads();
        #pragma unroll
        for (int ks = 0; ks < 2; ++ks) {
            short8 af[2], bf[4];
            #pragma unroll
            for (int m = 0; m < 2; ++m) {
                int row = wr_ * 32 + m * 16 + ar;
                int kb = (ks * 4 + g) ^ (row & 7);
                af[m] = *(const short8*)&Asw[row * 64 + kb * 8];
            }
            #pragma unroll
            for (int n = 0; n < 4; ++n) {
                int c = wc_ * 64 + n * 16 + ar;
                int kb = (ks * 4 + g) ^ (c & 7);
                bf[n] = *(const short8*)&Bsw[c * 64 + kb * 8];
            }
            #pragma unroll
            for (int m = 0; m < 2; ++m)
                #pragma unroll
                for (int n = 0; n < 4; ++n)
                    acc[m][n] = __builtin_amdgcn_mfma_f32_16x16x32_bf16(af[m], bf[n], acc[m][n], 0, 0, 0);
        }
        __syncthreads();
    }
    #pragma unroll
    for (int m = 0; m < 2; ++m) {
        #pragma unroll
        for (int n = 0; n < 4; ++n) {
            int cg = bn * 128 + wc_ * 64 + n * 16 + ar;
            int mg0 = m0 + wr_ * 32 + m * 16 + g * 4;
            if (cg < 256) {
                int head = cg >> 6, f = cg & 63;
                unsigned pk[2];
                pk[0] = pack_bf16(acc[m][n][0], acc[m][n][1]);
                pk[1] = pack_bf16(acc[m][n][2], acc[m][n][3]);
                *(uint2*)(hT + (size_t)(head * HF + f) * N + mg0) = *(uint2*)pk;
            } else {
                float bb = bias[cg - 256];
                #pragma unroll
                for (int r = 0; r < 4; ++r)
                    out[(size_t)(mg0 + r) * OUT_F + (cg - 256)] = acc[m][n][r] + bb;
            }
        }
    }
}

// K2: coe_i/coe_j from hT (column-major dot, coalesced)
__global__ __launch_bounds__(256) void k_coe(
    const unsigned short* __restrict__ hT, const float* __restrict__ wi,
    const float* __restrict__ wj, float* __restrict__ coe_i, float* __restrict__ coe_j)
{
    int head = blockIdx.y;
    int n = blockIdx.x * 256 + threadIdx.x;
    const unsigned short* hp = hT + (size_t)head * HF * N + n;
    float si = 0.f, sj = 0.f;
    #pragma unroll 8
    for (int f = 0; f < HF; ++f) {
        float hv = bf2f(hp[(size_t)f * N]);
        si = fmaf(hv, wi[head * HF + f], si);
        sj = fmaf(hv, wj[head * HF + f], sj);
    }
    coe_i[head * N + n] = si;
    coe_j[head * N + n] = sj;
}

// K3: per head: maxB + column factor arrays F=exp(b), H=exp(0.2b)
__global__ __launch_bounds__(256) void k_cols(
    const float* __restrict__ coe_j, float* __restrict__ maxB,
    float* __restrict__ F, float* __restrict__ H)
{
    __shared__ float red[256];
    int head = blockIdx.x;
    int t = threadIdx.x;
    float m = -1e30f;
    for (int n = t; n < N; n += 256) {
        float b = coe_j[head * N + n];
        F[head * N + n] = __expf(b);
        H[head * N + n] = __expf(0.2f * b);
        m = fmaxf(m, b);
    }
    red[t] = m;
    __syncthreads();
    for (int s = 128; s > 0; s >>= 1) {
        if (t < s) red[t] = fmaxf(red[t], red[t + s]);
        __syncthreads();
    }
    if (t == 0) maxB[head] = red[0];
}

// K4: pack graph -> bits[jw][i]: bit k = graph[jw*32+k][i] > 0
__global__ __launch_bounds__(256) void k_pack(
    const int* __restrict__ graph, unsigned int* __restrict__ bits)
{
    int i = blockIdx.y * 256 + threadIdx.x;
    int jw = blockIdx.x;
    const int* gp = graph + (size_t)(jw * 32) * N + i;
    unsigned int word = 0;
    #pragma unroll
    for (int k = 0; k < 32; ++k)
        word |= (gp[(size_t)k * N] > 0 ? 1u : 0u) << k;
    bits[(size_t)jw * N + i] = word;
}

// P for 8 columns: p = max(Ei*F, Gi*H) (= exp(lrelu(a+b)-M)), mask by sign-shift, cvt_pk to bf16
__device__ __forceinline__ short8 makeP(
    const float* __restrict__ Fp, const float* __restrict__ Hp, int jt,
    unsigned int mk, float Ei, float Gi)
{
    float4 fa = *(const float4*)(Fp + jt);
    float4 fb2 = *(const float4*)(Fp + jt + 4);
    float4 ha = *(const float4*)(Hp + jt);
    float4 hb2 = *(const float4*)(Hp + jt + 4);
    float fv[8] = {fa.x, fa.y, fa.z, fa.w, fb2.x, fb2.y, fb2.z, fb2.w};
    float hv[8] = {ha.x, ha.y, ha.z, ha.w, hb2.x, hb2.y, hb2.z, hb2.w};
    union { short8 s8; unsigned u[4]; } A;
    #pragma unroll
    for (int jp = 0; jp < 4; ++jp) {
        float p0 = fmaxf(Ei * fv[2 * jp],     Gi * hv[2 * jp]);
        float p1 = fmaxf(Ei * fv[2 * jp + 1], Gi * hv[2 * jp + 1]);
        int s0 = ((int)(mk << (31 - 2 * jp))) >> 31;
        int s1 = ((int)(mk << (30 - 2 * jp))) >> 31;
        p0 = __int_as_float(__float_as_int(p0) & s0);
        p1 = __int_as_float(__float_as_int(p1) & s1);
        A.u[jp] = pack_bf16(p0, p1);
    }
    return A.s8;
}

// K5: flash aggregate. 512 thr = 8 waves; wave-pair (wrow, grp) splits even/odd 64-j tiles.
// 2-deep double buffer, ONE barrier per 128-j superstep; merge buffer aliases hbuf.
// No min-waves clamp: let compiler pick VGPRs (round-5's (512,8) clamp caused spills).
__global__ __launch_bounds__(512) void k_att(
    const unsigned short* __restrict__ hT, const float* __restrict__ coe_i,
    const float* __restrict__ maxB, const float* __restrict__ F,
    const float* __restrict__ H, const unsigned int* __restrict__ bits,
    float* __restrict__ out)
{
    __shared__ char smem[32768];
    unsigned short* hb = (unsigned short*)smem;   // [buf:2][half:2][4096]
    float* mbuf = (float*)smem;                    // aliased merge buffer (used after final barrier)

    int t = threadIdx.x;
    int head = blockIdx.y;
    int i0 = blockIdx.x * 64;
    int w = t >> 6, l = t & 63;
    int wrow = w & 3, grp = w >> 2;
    int ar = l & 15, g = l >> 4, g8 = g * 8;

    int irow = i0 + wrow * 16 + ar;
    float a = coe_i[head * N + irow];
    float M = lrelu(a + maxB[head]);
    float Ei = __expf(a - M);
    float Gi = __expf(0.2f * a - M);

    f32x4 acc[4];
    #pragma unroll
    for (int fb = 0; fb < 4; ++fb) acc[fb] = (f32x4){0.f, 0.f, 0.f, 0.f};
    f32x4 accd = (f32x4){0.f, 0.f, 0.f, 0.f};

    short8 ones;
    #pragma unroll
    for (int k = 0; k < 8; ++k) ones[k] = (short)0x3F80;

    // staging role: thread stages 16 j of feature-row sf into half sbuf
    int sbuf = t >> 8;
    int u = t & 255;
    int sf = u >> 2, sj = (u & 3) * 16;
    const unsigned short* hrow = hT + ((size_t)(head * HF + sf) * N) + sj;
    int pg0 = ((sj >> 3) + 0) ^ (sf & 7);
    int pg1 = ((sj >> 3) + 1) ^ (sf & 7);
    int wo = sbuf * 4096 + sf * 64;

    const float* Fp = F + head * N + g8;
    const float* Hp = H + head * N + g8;
    const unsigned int* bp = bits + irow;

    // prolog: load superstep 0
    uint4 hv0 = *(const uint4*)(hrow + sbuf * 64);
    uint4 hv1 = *(const uint4*)(hrow + sbuf * 64 + 8);

    for (int s = 0; s < 64; ++s) {
        int jt = s * 128 + grp * 64;
        // bitmask gathers first (longest latency, L2)
        size_t jw = (size_t)(jt >> 5);
        unsigned int mk0 = bp[jw * N] >> g8;
        unsigned int mk1 = bp[(jw + 1) * N] >> g8;
        // write this superstep's staged tile (loaded last iteration)
        int bo = (s & 1) * 8192;
        *(uint4*)&hb[bo + wo + pg0 * 8] = hv0;
        *(uint4*)&hb[bo + wo + pg1 * 8] = hv1;
        // issue next superstep's stage loads (consumed next iteration)
        int sn = (s + 1 < 64) ? s + 1 : s;
        hv0 = *(const uint4*)(hrow + sn * 128 + sbuf * 64);
        hv1 = *(const uint4*)(hrow + sn * 128 + sbuf * 64 + 8);

        // P halves: each makeP loads+consumes its 16 floats immediately (low live range)
        short8 af0 = makeP(Fp, Hp, jt, mk0, Ei, Gi);
        short8 af1 = makeP(Fp, Hp, jt + 32, mk1, Ei, Gi);

        __syncthreads();   // single barrier: buf[s&1] visible; old reads of buf[(s+1)&1] done

        const unsigned short* rb = &hb[bo + grp * 4096];
        #pragma unroll
        for (int ss = 0; ss < 2; ++ss) {
            short8 af = ss ? af1 : af0;
            #pragma unroll
            for (int fb = 0; fb < 4; ++fb) {
                int row = fb * 16 + ar;
                int pg = (ss * 4 + g) ^ (ar & 7);
                short8 bfr = *(const short8*)&rb[row * 64 + pg * 8];
                acc[fb] = __builtin_amdgcn_mfma_f32_16x16x32_bf16(af, bfr, acc[fb], 0, 0, 0);
            }
            accd = __builtin_amdgcn_mfma_f32_16x16x32_bf16(af, ones, accd, 0, 0, 0);
        }
    }

    __syncthreads();               // all compute done before aliasing LDS as mbuf
    int mb = (wrow * 64 + l) * 21;
    if (grp == 1) {
        #pragma unroll
        for (int fb = 0; fb < 4; ++fb)
            #pragma unroll
            for (int r = 0; r < 4; ++r)
                mbuf[mb + fb * 4 + r] = acc[fb][r];
        #pragma unroll
        for (int r = 0; r < 4; ++r)
            mbuf[mb + 16 + r] = accd[r];
    }
    __syncthreads();
    if (grp == 0) {
        #pragma unroll
        for (int fb = 0; fb < 4; ++fb)
            #pragma unroll
            for (int r = 0; r < 4; ++r)
                acc[fb][r] += mbuf[mb + fb * 4 + r];
        #pragma unroll
        for (int r = 0; r < 4; ++r)
            accd[r] += mbuf[mb + 16 + r];
        #pragma unroll
        for (int r = 0; r < 4; ++r) {
            float inv = 1.0f / accd[r];
            int orow = i0 + wrow * 16 + g * 4 + r;
            float* op = out + (size_t)orow * OUT_F + head * HF + ar;
            #pragma unroll
            for (int fb = 0; fb < 4; ++fb)
                op[fb * 16] += acc[fb][r] * inv;
        }
    }
}

extern "C" void kernel_launch(void* const* d_in, const int* in_sizes, int n_in,
                              void* d_out, int out_size, void* d_ws, size_t ws_size,
                              hipStream_t stream) {
    const float* x     = (const float*)d_in[0];
    const int*   graph = (const int*)d_in[1];
    const float* w     = (const float*)d_in[2];
    const float* wi    = (const float*)d_in[3];
    const float* wj    = (const float*)d_in[4];
    const float* wr    = (const float*)d_in[5];
    const float* bias  = (const float*)d_in[6];
    float* out = (float*)d_out;

    char* ws = (char*)d_ws;
    unsigned short* hT  = (unsigned short*)(ws);                    // 4,194,304
    float* coe_i = (float*)(ws + 4194304);                          // 131072
    float* coe_j = (float*)(ws + 4325376);                          // 131072
    float* maxB  = (float*)(ws + 4456448);                          // 1024
    float* F     = (float*)(ws + 4457472);                          // 131072
    float* H     = (float*)(ws + 4588544);                          // 131072
    unsigned short* BbT = (unsigned short*)(ws + 4719616);          // 262144
    unsigned int* bits  = (unsigned int*)(ws + 4981760);            // 8,388,608

    k_wcvt<<<dim3(512), 256, 0, stream>>>(w, wr, BbT);
    k_gemm<<<dim3(128, 4), 256, 0, stream>>>(x, BbT, bias, hT, out);
    k_coe<<<dim3(32, 4), 256, 0, stream>>>(hT, wi, wj, coe_i, coe_j);
    k_cols<<<dim3(4), 256, 0, stream>>>(coe_j, maxB, F, H);
    k_pack<<<dim3(256, 32), 256, 0, stream>>>(graph, bits);
    k_att<<<dim3(N / 64, HEADS), 512, 0, stream>>>(hT, coe_i, maxB, F, H, bits, out);
}

// Round 7
// 169.065 us; speedup vs baseline: 1.5047x; 1.0554x over previous
//
#include <hip/hip_runtime.h>
#include <hip/hip_bf16.h>

#define N 8192
#define IN_F 256
#define HEADS 4
#define HF 64
#define OUT_F 256

typedef __attribute__((ext_vector_type(8))) short short8;
typedef __attribute__((ext_vector_type(4))) float f32x4;

__device__ __forceinline__ float lrelu(float x) {
    return fmaxf(x, 0.0f) * 0.8f + x * 0.2f;
}
__device__ __forceinline__ short f2bf(float f) {
    union { __hip_bfloat16 h; short s; } u;
    u.h = __float2bfloat16(f);
    return u.s;
}
__device__ __forceinline__ float bf2f(unsigned short b) {
    union { unsigned u; float f; } v; v.u = ((unsigned)b) << 16;
    return v.f;
}
__device__ __forceinline__ unsigned pack_bf16(float p0, float p1) {
    union { __hip_bfloat162 b; unsigned u; } cv;
    cv.b = __float22bfloat162_rn(make_float2(p0, p1));
    return cv.u;
}

// K0: build BbT[c][k] bf16, c<256 -> W heads, c>=256 -> Wr
__global__ __launch_bounds__(256) void k_wcvt(
    const float* __restrict__ w, const float* __restrict__ wr,
    unsigned short* __restrict__ BbT)
{
    int c = blockIdx.x;
    int k = threadIdx.x;
    float v;
    if (c < 256) {
        int head = c >> 6, f = c & 63;
        v = w[((size_t)head * IN_F + k) * HF + f];
    } else {
        v = wr[(size_t)k * OUT_F + (c - 256)];
    }
    BbT[(size_t)c * IN_F + k] = (unsigned short)f2bf(v);
}

// K1: fused GEMM [8192x256]@[256x512] -> hT (cols<256, bf16, transposed) | out residual (cols>=256, f32)
__global__ __launch_bounds__(256) void k_gemm(
    const float* __restrict__ x, const unsigned short* __restrict__ BbT,
    const float* __restrict__ bias,
    unsigned short* __restrict__ hT, float* __restrict__ out)
{
    __shared__ unsigned short Asw[64 * 64];
    __shared__ unsigned short Bsw[128 * 64];
    int t = threadIdx.x;
    int m0 = blockIdx.x * 64;
    int bn = blockIdx.y;
    int w_ = t >> 6, l = t & 63;
    int wr_ = w_ >> 1, wc_ = w_ & 1;
    int ar = l & 15, g = l >> 4;

    f32x4 acc[2][4];
    #pragma unroll
    for (int m = 0; m < 2; ++m)
        #pragma unroll
        for (int n = 0; n < 4; ++n) acc[m][n] = (f32x4){0.f, 0.f, 0.f, 0.f};

    int srow = t >> 2, skq = (t & 3) * 16;
    int sc = t >> 1, sh = (t & 1) * 32;

    for (int kt = 0; kt < 4; ++kt) {
        const float* xs = x + (size_t)(m0 + srow) * IN_F + kt * 64 + skq;
        float4 xa = ((const float4*)xs)[0];
        float4 xb = ((const float4*)xs)[1];
        float4 xc = ((const float4*)xs)[2];
        float4 xd = ((const float4*)xs)[3];
        unsigned ae[8];
        ae[0] = pack_bf16(xa.x, xa.y); ae[1] = pack_bf16(xa.z, xa.w);
        ae[2] = pack_bf16(xb.x, xb.y); ae[3] = pack_bf16(xb.z, xb.w);
        ae[4] = pack_bf16(xc.x, xc.y); ae[5] = pack_bf16(xc.z, xc.w);
        ae[6] = pack_bf16(xd.x, xd.y); ae[7] = pack_bf16(xd.z, xd.w);
        int kb0 = (skq >> 3) ^ (srow & 7);
        int kb1 = ((skq >> 3) + 1) ^ (srow & 7);
        *(uint4*)&Asw[srow * 64 + kb0 * 8] = *(uint4*)&ae[0];
        *(uint4*)&Asw[srow * 64 + kb1 * 8] = *(uint4*)&ae[4];
        const unsigned short* bs = BbT + (size_t)(bn * 128 + sc) * IN_F + kt * 64 + sh;
        uint4 b0 = ((const uint4*)bs)[0];
        uint4 b1 = ((const uint4*)bs)[1];
        uint4 b2 = ((const uint4*)bs)[2];
        uint4 b3 = ((const uint4*)bs)[3];
        int hb = sh >> 3;
        *(uint4*)&Bsw[sc * 64 + ((hb + 0) ^ (sc & 7)) * 8] = b0;
        *(uint4*)&Bsw[sc * 64 + ((hb + 1) ^ (sc & 7)) * 8] = b1;
        *(uint4*)&Bsw[sc * 64 + ((hb + 2) ^ (sc & 7)) * 8] = b2;
        *(uint4*)&Bsw[sc * 64 + ((hb + 3) ^ (sc & 7)) * 8] = b3;
        __syncthreads();
        #pragma unroll
        for (int ks = 0; ks < 2; ++ks) {
            short8 af[2], bf[4];
            #pragma unroll
            for (int m = 0; m < 2; ++m) {
                int row = wr_ * 32 + m * 16 + ar;
                int kb = (ks * 4 + g) ^ (row & 7);
                af[m] = *(const short8*)&Asw[row * 64 + kb * 8];
            }
            #pragma unroll
            for (int n = 0; n < 4; ++n) {
                int c = wc_ * 64 + n * 16 + ar;
                int kb = (ks * 4 + g) ^ (c & 7);
                bf[n] = *(const short8*)&Bsw[c * 64 + kb * 8];
            }
            #pragma unroll
            for (int m = 0; m < 2; ++m)
                #pragma unroll
                for (int n = 0; n < 4; ++n)
                    acc[m][n] = __builtin_amdgcn_mfma_f32_16x16x32_bf16(af[m], bf[n], acc[m][n], 0, 0, 0);
        }
        __syncthreads();
    }
    #pragma unroll
    for (int m = 0; m < 2; ++m) {
        #pragma unroll
        for (int n = 0; n < 4; ++n) {
            int cg = bn * 128 + wc_ * 64 + n * 16 + ar;
            int mg0 = m0 + wr_ * 32 + m * 16 + g * 4;
            if (cg < 256) {
                int head = cg >> 6, f = cg & 63;
                unsigned pk[2];
                pk[0] = pack_bf16(acc[m][n][0], acc[m][n][1]);
                pk[1] = pack_bf16(acc[m][n][2], acc[m][n][3]);
                *(uint2*)(hT + (size_t)(head * HF + f) * N + mg0) = *(uint2*)pk;
            } else {
                float bb = bias[cg - 256];
                #pragma unroll
                for (int r = 0; r < 4; ++r)
                    out[(size_t)(mg0 + r) * OUT_F + (cg - 256)] = acc[m][n][r] + bb;
            }
        }
    }
}

// K2: coe_i/coe_j from hT (column-major dot, coalesced)
__global__ __launch_bounds__(256) void k_coe(
    const unsigned short* __restrict__ hT, const float* __restrict__ wi,
    const float* __restrict__ wj, float* __restrict__ coe_i, float* __restrict__ coe_j)
{
    int head = blockIdx.y;
    int n = blockIdx.x * 256 + threadIdx.x;
    const unsigned short* hp = hT + (size_t)head * HF * N + n;
    float si = 0.f, sj = 0.f;
    #pragma unroll 8
    for (int f = 0; f < HF; ++f) {
        float hv = bf2f(hp[(size_t)f * N]);
        si = fmaf(hv, wi[head * HF + f], si);
        sj = fmaf(hv, wj[head * HF + f], sj);
    }
    coe_i[head * N + n] = si;
    coe_j[head * N + n] = sj;
}

// K3: per head: maxB + column factor arrays F=exp(b), H=exp(0.2b)
__global__ __launch_bounds__(256) void k_cols(
    const float* __restrict__ coe_j, float* __restrict__ maxB,
    float* __restrict__ F, float* __restrict__ H)
{
    __shared__ float red[256];
    int head = blockIdx.x;
    int t = threadIdx.x;
    float m = -1e30f;
    for (int n = t; n < N; n += 256) {
        float b = coe_j[head * N + n];
        F[head * N + n] = __expf(b);
        H[head * N + n] = __expf(0.2f * b);
        m = fmaxf(m, b);
    }
    red[t] = m;
    __syncthreads();
    for (int s = 128; s > 0; s >>= 1) {
        if (t < s) red[t] = fmaxf(red[t], red[t + s]);
        __syncthreads();
    }
    if (t == 0) maxB[head] = red[0];
}

// K4: pack graph -> bits[jw][i]: bit k = graph[jw*32+k][i] > 0
__global__ __launch_bounds__(256) void k_pack(
    const int* __restrict__ graph, unsigned int* __restrict__ bits)
{
    int i = blockIdx.y * 256 + threadIdx.x;
    int jw = blockIdx.x;
    const int* gp = graph + (size_t)(jw * 32) * N + i;
    unsigned int word = 0;
    #pragma unroll
    for (int k = 0; k < 32; ++k)
        word |= (gp[(size_t)k * N] > 0 ? 1u : 0u) << k;
    bits[(size_t)jw * N + i] = word;
}

// P for 8 columns: p = max(Ei*F, Gi*H) (= exp(lrelu(a+b)-M)), mask by sign-shift, cvt_pk to bf16
__device__ __forceinline__ short8 makeP(
    const float4& fa, const float4& fb4, const float4& ha, const float4& hb4,
    unsigned int mk, float Ei, float Gi)
{
    float fv[8] = {fa.x, fa.y, fa.z, fa.w, fb4.x, fb4.y, fb4.z, fb4.w};
    float hv[8] = {ha.x, ha.y, ha.z, ha.w, hb4.x, hb4.y, hb4.z, hb4.w};
    union { short8 s8; unsigned u[4]; } A;
    #pragma unroll
    for (int jp = 0; jp < 4; ++jp) {
        float p0 = fmaxf(Ei * fv[2 * jp],     Gi * hv[2 * jp]);
        float p1 = fmaxf(Ei * fv[2 * jp + 1], Gi * hv[2 * jp + 1]);
        int s0 = ((int)(mk << (31 - 2 * jp))) >> 31;
        int s1 = ((int)(mk << (30 - 2 * jp))) >> 31;
        p0 = __int_as_float(__float_as_int(p0) & s0);
        p1 = __int_as_float(__float_as_int(p1) & s1);
        A.u[jp] = pack_bf16(p0, p1);
    }
    return A.s8;
}

// K5: flash aggregate, M=32 rows/wave. 8 waves = (rg:2 row-halves) x (grp:4 j-tiles).
// Superstep = 256 j staged (4 x 64j tiles, XOR-swizzled); each B-fragment ds_read
// feeds TWO row-group MFMAs (halves LDS read/j vs round 6). Single barrier/superstep,
// 2-deep double buffer (64 KB). 4-way grp merge via aliased LDS at the end.
__global__ __launch_bounds__(512) void k_att(
    const unsigned short* __restrict__ hT, const float* __restrict__ coe_i,
    const float* __restrict__ maxB, const float* __restrict__ F,
    const float* __restrict__ H, const unsigned int* __restrict__ bits,
    float* __restrict__ out)
{
    __shared__ char smem[65536];
    unsigned short* hb = (unsigned short*)smem;   // [buf:2][grp:4][f:64][j:64 swizzled]
    float* mbuf = (float*)smem;                    // aliased merge buffer

    int t = threadIdx.x;
    int head = blockIdx.y;
    int i0 = blockIdx.x * 64;
    int w = t >> 6, l = t & 63;
    int rg = w >> 2, grp = w & 3;
    int ar = l & 15, g = l >> 4, g8 = g * 8;

    int irow0 = i0 + rg * 32 + ar;        // m=0 row
    int irow1 = irow0 + 16;               // m=1 row
    float mB = maxB[head];
    float a0 = coe_i[head * N + irow0];
    float a1 = coe_i[head * N + irow1];
    float M0 = lrelu(a0 + mB);
    float M1 = lrelu(a1 + mB);
    float Ei0 = __expf(a0 - M0), Gi0 = __expf(0.2f * a0 - M0);
    float Ei1 = __expf(a1 - M1), Gi1 = __expf(0.2f * a1 - M1);

    f32x4 acc0[4], acc1[4];
    #pragma unroll
    for (int fb = 0; fb < 4; ++fb) {
        acc0[fb] = (f32x4){0.f, 0.f, 0.f, 0.f};
        acc1[fb] = (f32x4){0.f, 0.f, 0.f, 0.f};
    }
    f32x4 accd0 = (f32x4){0.f, 0.f, 0.f, 0.f};
    f32x4 accd1 = (f32x4){0.f, 0.f, 0.f, 0.f};

    short8 ones;
    #pragma unroll
    for (int k = 0; k < 8; ++k) ones[k] = (short)0x3F80;

    // staging role: lane u stages 4 granules (64B) of row sf in tile grp_s
    int grp_s = t >> 7;
    int v = t & 127;
    int sf = v >> 1;
    int gsel = v & 1;
    const unsigned short* hsrc = hT + ((size_t)(head * HF + sf) * N) + grp_s * 64 + gsel * 32;
    int sfk = sf & 7;
    int wbase = grp_s * 4096 + sf * 64;
    int pgA = ((gsel * 4 + 0) ^ sfk) * 8;
    int pgB = ((gsel * 4 + 1) ^ sfk) * 8;
    int pgC = ((gsel * 4 + 2) ^ sfk) * 8;
    int pgD = ((gsel * 4 + 3) ^ sfk) * 8;

    const float* Fp = F + head * N + g8;
    const float* Hp = H + head * N + g8;
    const unsigned int* bp0 = bits + irow0;
    const unsigned int* bp1 = bits + irow1;

    // prolog: load superstep 0 staging
    uint4 hv0 = *(const uint4*)(hsrc + 0);
    uint4 hv1 = *(const uint4*)(hsrc + 8);
    uint4 hv2 = *(const uint4*)(hsrc + 16);
    uint4 hv3 = *(const uint4*)(hsrc + 24);

    for (int s = 0; s < 32; ++s) {
        int jt = s * 256 + grp * 64;
        // mask gathers (L2 latency) first
        size_t jw = (size_t)(jt >> 5);
        unsigned int mk00 = bp0[jw * N] >> g8;
        unsigned int mk01 = bp0[(jw + 1) * N] >> g8;
        unsigned int mk10 = bp1[jw * N] >> g8;
        unsigned int mk11 = bp1[(jw + 1) * N] >> g8;
        // write staged tile (loaded last iteration) into buf s&1
        int bo = (s & 1) * 16384;
        *(uint4*)&hb[bo + wbase + pgA] = hv0;
        *(uint4*)&hb[bo + wbase + pgB] = hv1;
        *(uint4*)&hb[bo + wbase + pgC] = hv2;
        *(uint4*)&hb[bo + wbase + pgD] = hv3;
        // issue next superstep's stage loads
        int sn = (s + 1 < 32) ? s + 1 : s;
        const unsigned short* hn = hsrc + (size_t)sn * 256;
        hv0 = *(const uint4*)(hn + 0);
        hv1 = *(const uint4*)(hn + 8);
        hv2 = *(const uint4*)(hn + 16);
        hv3 = *(const uint4*)(hn + 24);

        // P fragments: per ss load F/H once, use for both row-groups
        float4 fa0 = *(const float4*)(Fp + jt);
        float4 fb0 = *(const float4*)(Fp + jt + 4);
        float4 ha0 = *(const float4*)(Hp + jt);
        float4 hb0 = *(const float4*)(Hp + jt + 4);
        short8 af00 = makeP(fa0, fb0, ha0, hb0, mk00, Ei0, Gi0);
        short8 af10 = makeP(fa0, fb0, ha0, hb0, mk10, Ei1, Gi1);
        float4 fa1 = *(const float4*)(Fp + jt + 32);
        float4 fb1 = *(const float4*)(Fp + jt + 36);
        float4 ha1 = *(const float4*)(Hp + jt + 32);
        float4 hb1 = *(const float4*)(Hp + jt + 36);
        short8 af01 = makeP(fa1, fb1, ha1, hb1, mk01, Ei0, Gi0);
        short8 af11 = makeP(fa1, fb1, ha1, hb1, mk11, Ei1, Gi1);

        __syncthreads();   // buf s&1 staged; prior reads of buf (s+1)&1 long done

        const unsigned short* rb = &hb[bo + grp * 4096];
        #pragma unroll
        for (int ss = 0; ss < 2; ++ss) {
            short8 a0f = ss ? af01 : af00;
            short8 a1f = ss ? af11 : af10;
            #pragma unroll
            for (int fb = 0; fb < 4; ++fb) {
                int row = fb * 16 + ar;
                int pg = (ss * 4 + g) ^ (ar & 7);
                short8 bfr = *(const short8*)&rb[row * 64 + pg * 8];
                acc0[fb] = __builtin_amdgcn_mfma_f32_16x16x32_bf16(a0f, bfr, acc0[fb], 0, 0, 0);
                acc1[fb] = __builtin_amdgcn_mfma_f32_16x16x32_bf16(a1f, bfr, acc1[fb], 0, 0, 0);
            }
            accd0 = __builtin_amdgcn_mfma_f32_16x16x32_bf16(a0f, ones, accd0, 0, 0, 0);
            accd1 = __builtin_amdgcn_mfma_f32_16x16x32_bf16(a1f, ones, accd1, 0, 0, 0);
        }
    }

    // 4-way grp merge through aliased LDS
    __syncthreads();
    int slot = rg * 64 + l;
    if (grp > 0) {
        float* dst = mbuf + (size_t)(grp - 1) * 5248 + slot * 41;
        #pragma unroll
        for (int fb = 0; fb < 4; ++fb)
            #pragma unroll
            for (int r = 0; r < 4; ++r) {
                dst[fb * 4 + r] = acc0[fb][r];
                dst[16 + fb * 4 + r] = acc1[fb][r];
            }
        #pragma unroll
        for (int r = 0; r < 4; ++r) {
            dst[32 + r] = accd0[r];
            dst[36 + r] = accd1[r];
        }
    }
    __syncthreads();
    if (grp == 0) {
        #pragma unroll
        for (int q = 0; q < 3; ++q) {
            const float* src = mbuf + (size_t)q * 5248 + slot * 41;
            #pragma unroll
            for (int fb = 0; fb < 4; ++fb)
                #pragma unroll
                for (int r = 0; r < 4; ++r) {
                    acc0[fb][r] += src[fb * 4 + r];
                    acc1[fb][r] += src[16 + fb * 4 + r];
                }
            #pragma unroll
            for (int r = 0; r < 4; ++r) {
                accd0[r] += src[32 + r];
                accd1[r] += src[36 + r];
            }
        }
        #pragma unroll
        for (int r = 0; r < 4; ++r) {
            float inv0 = 1.0f / accd0[r];
            float inv1 = 1.0f / accd1[r];
            int orow0 = i0 + rg * 32 + g * 4 + r;
            float* op0 = out + (size_t)orow0 * OUT_F + head * HF + ar;
            float* op1 = op0 + 16 * OUT_F;
            #pragma unroll
            for (int fb = 0; fb < 4; ++fb) {
                op0[fb * 16] += acc0[fb][r] * inv0;
                op1[fb * 16] += acc1[fb][r] * inv1;
            }
        }
    }
}

extern "C" void kernel_launch(void* const* d_in, const int* in_sizes, int n_in,
                              void* d_out, int out_size, void* d_ws, size_t ws_size,
                              hipStream_t stream) {
    const float* x     = (const float*)d_in[0];
    const int*   graph = (const int*)d_in[1];
    const float* w     = (const float*)d_in[2];
    const float* wi    = (const float*)d_in[3];
    const float* wj    = (const float*)d_in[4];
    const float* wr    = (const float*)d_in[5];
    const float* bias  = (const float*)d_in[6];
    float* out = (float*)d_out;

    char* ws = (char*)d_ws;
    unsigned short* hT  = (unsigned short*)(ws);                    // 4,194,304
    float* coe_i = (float*)(ws + 4194304);                          // 131072
    float* coe_j = (float*)(ws + 4325376);                          // 131072
    float* maxB  = (float*)(ws + 4456448);                          // 1024
    float* F     = (float*)(ws + 4457472);                          // 131072
    float* H     = (float*)(ws + 4588544);                          // 131072
    unsigned short* BbT = (unsigned short*)(ws + 4719616);          // 262144
    unsigned int* bits  = (unsigned int*)(ws + 4981760);            // 8,388,608

    k_wcvt<<<dim3(512), 256, 0, stream>>>(w, wr, BbT);
    k_gemm<<<dim3(128, 4), 256, 0, stream>>>(x, BbT, bias, hT, out);
    k_coe<<<dim3(32, 4), 256, 0, stream>>>(hT, wi, wj, coe_i, coe_j);
    k_cols<<<dim3(4), 256, 0, stream>>>(coe_j, maxB, F, H);
    k_pack<<<dim3(256, 32), 256, 0, stream>>>(graph, bits);
    k_att<<<dim3(N / 64, HEADS), 512, 0, stream>>>(hT, coe_i, maxB, F, H, bits, out);
}